// Round 1
// baseline (526.199 us; speedup 1.0000x reference)
//
#include <hip/hip_runtime.h>
#include <hip/hip_bf16.h>

#define B_ 2
#define S_ 2048
#define D_ 1024
#define H_ 16
#define DK_ 64
#define FF_ 4096
#define M_ (B_ * S_)  // 4096 rows

typedef unsigned short u16;
typedef __bf16 bf16x8 __attribute__((ext_vector_type(8)));
typedef float f32x4 __attribute__((ext_vector_type(4)));
typedef u16 u16x4 __attribute__((ext_vector_type(4)));
typedef u16 u16x8 __attribute__((ext_vector_type(8)));

__device__ __forceinline__ u16 f2bf(float f) {
  __bf16 b = (__bf16)f;
  return __builtin_bit_cast(u16, b);
}
__device__ __forceinline__ float bf2f(u16 u) {
  __bf16 b = __builtin_bit_cast(__bf16, u);
  return (float)b;
}

// async global->LDS, 16B per lane. LDS dest is wave-uniform base + lane*16.
__device__ __forceinline__ void async_lds16(const void* g, void* l) {
  __builtin_amdgcn_global_load_lds(
      (const __attribute__((address_space(1))) unsigned int*)g,
      (__attribute__((address_space(3))) unsigned int*)l, 16, 0, 0);
}

// ---------------------------------------------------------------------------
// f32 -> bf16 convert (weights)
__global__ __launch_bounds__(256) void f2b_k(const float* __restrict__ in,
                                             u16* __restrict__ out, int n4) {
  int idx = blockIdx.x * 256 + threadIdx.x;
  if (idx < n4) {
    float4 v = *(const float4*)(in + (size_t)idx * 4);
    u16x4 o;
    o[0] = f2bf(v.x); o[1] = f2bf(v.y); o[2] = f2bf(v.z); o[3] = f2bf(v.w);
    *(u16x4*)(out + (size_t)idx * 4) = o;
  }
}

// ---------------------------------------------------------------------------
// RMSNorm: f32 [rows][1024] -> bf16, block per row, 256 threads * 4 cols
__global__ __launch_bounds__(256) void rmsnorm_k(const float* __restrict__ X,
                                                 const float* __restrict__ G,
                                                 u16* __restrict__ Out) {
  const int row = blockIdx.x, tid = threadIdx.x;
  const float4 xv = *(const float4*)(X + (size_t)row * D_ + tid * 4);
  float ss = xv.x * xv.x + xv.y * xv.y + xv.z * xv.z + xv.w * xv.w;
#pragma unroll
  for (int off = 1; off < 64; off <<= 1) ss += __shfl_xor(ss, off);
  __shared__ float red[4];
  if ((tid & 63) == 0) red[tid >> 6] = ss;
  __syncthreads();
  const float tot = red[0] + red[1] + red[2] + red[3];
  const float sc = rsqrtf(tot * (1.0f / D_) + 1e-5f);
  const float4 gv = *(const float4*)(G + tid * 4);
  u16x4 o;
  o[0] = f2bf(xv.x * sc * gv.x);
  o[1] = f2bf(xv.y * sc * gv.y);
  o[2] = f2bf(xv.z * sc * gv.z);
  o[3] = f2bf(xv.w * sc * gv.w);
  *(u16x4*)(Out + (size_t)row * D_ + tid * 4) = o;
}

// ---------------------------------------------------------------------------
// RoPE in-place on bf16 [4096][1024] viewed as uints (pairs). 8192 blocks.
__global__ __launch_bounds__(256) void rope_k(unsigned int* __restrict__ buf,
                                              const int* __restrict__ pos) {
  const int idx = blockIdx.x * 256 + threadIdx.x;  // < 4096*512
  const int row = idx >> 9, p = idx & 511;
  const int i = p & 31;  // pair index within head
  unsigned int v = buf[(size_t)row * 512 + p];
  const float xr = bf2f((u16)(v & 0xffffu));
  const float xi = bf2f((u16)(v >> 16));
  // inv_freq = theta^(-2i/64) = exp(-i/32 * ln(10000))
  const float ang =
      (float)pos[row] * __expf(-(float)i * (9.210340371976184f / 32.0f));
  float sn, cs;
  sincosf(ang, &sn, &cs);
  const float orr = xr * cs - xi * sn;
  const float oii = xr * sn + xi * cs;
  buf[(size_t)row * 512 + p] =
      (unsigned int)f2bf(orr) | ((unsigned int)f2bf(oii) << 16);
}

// ---------------------------------------------------------------------------
// V [4096][1024] bf16 -> Vt [32 bh][64 dk][2048 s] bf16 (per-head transpose)
__global__ __launch_bounds__(256) void transpose_v(const u16* __restrict__ V,
                                                   u16* __restrict__ Vt) {
  __shared__ __align__(16) u16 tile[32][64];
  const int tid = threadIdx.x;
  const int s0 = blockIdx.x * 32, bh = blockIdx.y, b = bh >> 4, h = bh & 15;
  {
    const int sr = tid >> 3, c = tid & 7;
    *(u16x8*)&tile[sr][c * 8] =
        *(const u16x8*)(V + (size_t)(b * S_ + s0 + sr) * D_ + h * DK_ + c * 8);
  }
  __syncthreads();
  {
    const int dk = tid >> 2, cs = tid & 3;
    u16x8 vv;
#pragma unroll
    for (int j = 0; j < 8; ++j) vv[j] = tile[cs * 8 + j][dk];
    *(u16x8*)(Vt + (size_t)(bh * DK_ + dk) * S_ + s0 + cs * 8) = vv;
  }
}

// ---------------------------------------------------------------------------
// GEMM: C[M,N] = A[M,K] @ Bw[N,K]^T   (bf16 in, f32 acc)
// 128x128 tile, BK=32, 256 threads (4 waves, 2x2 of 64x64).
// EPI 0: store bf16. EPI 1: f32 store of aux(f32) + acc. EPI 2: swiglu:
//        store bf16( silu(aux_bf16) * acc ).
template <int EPI>
__global__ __launch_bounds__(256) void gemm_bt(const u16* __restrict__ A,
                                               const u16* __restrict__ Bw,
                                               void* __restrict__ Cout,
                                               const void* __restrict__ auxp,
                                               int N, int K) {
  __shared__ __align__(16) u16 As[128 * 32];
  __shared__ __align__(16) u16 Bs[128 * 32];
  const int tid = threadIdx.x;
  const int l = tid & 63, w = tid >> 6;
  const int m0 = blockIdx.y * 128, n0 = blockIdx.x * 128;
  const int wm = (w >> 1) * 64, wn = (w & 1) * 64;
  const int lr = l & 15, lg = l >> 4;

  f32x4 acc[4][4] = {};
  const int sA0 = w * 128;  // wave's first 16B slot (of 512)

  for (int k0 = 0; k0 < K; k0 += 32) {
#pragma unroll
    for (int inst = 0; inst < 2; ++inst) {
      const int s = sA0 + inst * 64 + l;      // slot: row = s>>2, c16 = s&3
      const int row = s >> 2, c = s & 3;
      async_lds16(A + (size_t)(m0 + row) * K + k0 + c * 8,
                  (char*)As + (sA0 + inst * 64) * 16);
      async_lds16(Bw + (size_t)(n0 + row) * K + k0 + c * 8,
                  (char*)Bs + (sA0 + inst * 64) * 16);
    }
    __syncthreads();  // drains vmcnt -> staged tile visible
    bf16x8 af[4], bfr[4];
#pragma unroll
    for (int i = 0; i < 4; ++i)
      af[i] = *(const bf16x8*)&As[(wm + i * 16 + lr) * 32 + lg * 8];
#pragma unroll
    for (int j = 0; j < 4; ++j)
      bfr[j] = *(const bf16x8*)&Bs[(wn + j * 16 + lr) * 32 + lg * 8];
#pragma unroll
    for (int i = 0; i < 4; ++i)
#pragma unroll
      for (int j = 0; j < 4; ++j)
        acc[i][j] = __builtin_amdgcn_mfma_f32_16x16x32_bf16(af[i], bfr[j],
                                                            acc[i][j], 0, 0, 0);
    __syncthreads();  // protect LDS before next stage
  }

  // epilogue: C/D layout col = l&15, row = (l>>4)*4 + t  [m89-verified]
#pragma unroll
  for (int i = 0; i < 4; ++i) {
#pragma unroll
    for (int j = 0; j < 4; ++j) {
#pragma unroll
      for (int t = 0; t < 4; ++t) {
        const int grow = m0 + wm + i * 16 + lg * 4 + t;
        const int gcol = n0 + wn + j * 16 + lr;
        const size_t idx = (size_t)grow * N + gcol;
        const float v = acc[i][j][t];
        if (EPI == 0) {
          ((u16*)Cout)[idx] = f2bf(v);
        } else if (EPI == 1) {
          ((float*)Cout)[idx] = ((const float*)auxp)[idx] + v;
        } else {
          const float av = bf2f(((const u16*)auxp)[idx]);
          const float sw = av / (1.f + __expf(-av));
          ((u16*)Cout)[idx] = f2bf(sw * v);
        }
      }
    }
  }
}

// ---------------------------------------------------------------------------
// Causal flash attention. Q,K: [4096][1024] bf16 (post-RoPE),
// Vt: [32][64][2048] bf16. O: [4096][1024] bf16.
// Grid (S/64, B*H); 4 waves, 16 q-rows each; kv tiles of 32.
__global__ __launch_bounds__(256) void attn_fwd(const u16* __restrict__ Q,
                                                const u16* __restrict__ K,
                                                const u16* __restrict__ Vt,
                                                u16* __restrict__ O) {
  __shared__ __align__(16) u16 Ks[32 * 64];     // [kv][dk], XOR-swizzled
  __shared__ __align__(16) u16 Vs[64 * 32];     // [dk][kv] (from Vt), linear
  __shared__ __align__(16) u16 Ps[4][16 * 32];  // per-wave P tile
  const int tid = threadIdx.x, l = tid & 63, w = tid >> 6;
  const int q0 = blockIdx.x * 64;
  const int bh = blockIdx.y, b = bh >> 4, h = bh & 15;
  const int q0w = q0 + w * 16;
  const int lr = l & 15, lg = l >> 4;

  bf16x8 aq[2];
  {
    const u16* qp = Q + (size_t)(b * S_ + q0w + lr) * D_ + h * DK_ + lg * 8;
    aq[0] = *(const bf16x8*)qp;
    aq[1] = *(const bf16x8*)(qp + 32);
  }
  f32x4 oacc[4] = {};
  float mrow[4], lrow[4];
#pragma unroll
  for (int t = 0; t < 4; ++t) { mrow[t] = -1e30f; lrow[t] = 0.f; }

  const int ntiles = blockIdx.x * 2 + 2;
  for (int it = 0; it < ntiles; ++it) {
    const int kv0 = it * 32;
    {
      // K tile: LDS (kr, c) holds global chunk (kr, c ^ (kr&7))
      const int kr = tid >> 3, c = tid & 7;
      async_lds16(
          K + (size_t)(b * S_ + kv0 + kr) * D_ + h * DK_ + ((c ^ (kr & 7)) * 8),
          (char*)Ks + w * 1024);
      // V^T tile: [64 dk][32 kv] linear (64B rows -> conflict-free b128)
      const int dr = tid >> 2, c2 = tid & 3;
      async_lds16(Vt + (size_t)(bh * DK_ + dr) * S_ + kv0 + c2 * 8,
                  (char*)Vs + w * 1024);
    }
    __syncthreads();
    // QK^T: S[q][kv], A=Q rows, B cols = kv (K rows, dk contiguous)
    f32x4 sf[2];
#pragma unroll
    for (int n = 0; n < 2; ++n) {
      f32x4 z = {};
      const int kvr = n * 16 + lr;
#pragma unroll
      for (int ss = 0; ss < 2; ++ss) {
        const int cw = lg + ss * 4;
        bf16x8 bk = *(const bf16x8*)&Ks[kvr * 64 + ((cw ^ (kvr & 7)) * 8)];
        z = __builtin_amdgcn_mfma_f32_16x16x32_bf16(aq[ss], bk, z, 0, 0, 0);
      }
      sf[n] = z;
    }
    // online softmax, rows r = lg*4+t spread over 16 lanes (cols)
    float corr[4];
#pragma unroll
    for (int t = 0; t < 4; ++t) {
      const int qrow = q0w + lg * 4 + t;
      float v0 = (kv0 + lr <= qrow) ? sf[0][t] * 0.125f : -1e30f;
      float v1 = (kv0 + 16 + lr <= qrow) ? sf[1][t] * 0.125f : -1e30f;
      float mx = fmaxf(v0, v1);
#pragma unroll
      for (int off = 1; off < 16; off <<= 1) mx = fmaxf(mx, __shfl_xor(mx, off));
      const float nm = fmaxf(mrow[t], mx);
      const float e0 = __expf(v0 - nm), e1 = __expf(v1 - nm);
      float ps = e0 + e1;
#pragma unroll
      for (int off = 1; off < 16; off <<= 1) ps += __shfl_xor(ps, off);
      corr[t] = __expf(mrow[t] - nm);
      lrow[t] = lrow[t] * corr[t] + ps;
      mrow[t] = nm;
      Ps[w][(lg * 4 + t) * 32 + lr] = f2bf(e0);
      Ps[w][(lg * 4 + t) * 32 + 16 + lr] = f2bf(e1);
    }
#pragma unroll
    for (int d = 0; d < 4; ++d)
#pragma unroll
      for (int t = 0; t < 4; ++t) oacc[d][t] *= corr[t];
    __syncthreads();  // orders P write -> P fragment read (uniform flow)
    // PV: A = P (16x32), B = V (32 kv x 64 dk) from Vt rows
    bf16x8 ap = *(const bf16x8*)&Ps[w][lr * 32 + lg * 8];
#pragma unroll
    for (int d = 0; d < 4; ++d) {
      bf16x8 bv = *(const bf16x8*)&Vs[(d * 16 + lr) * 32 + lg * 8];
      oacc[d] = __builtin_amdgcn_mfma_f32_16x16x32_bf16(ap, bv, oacc[d], 0, 0, 0);
    }
    __syncthreads();  // protect Ks/Vs before next stage
  }
#pragma unroll
  for (int d = 0; d < 4; ++d) {
#pragma unroll
    for (int t = 0; t < 4; ++t) {
      const size_t idx =
          (size_t)(b * S_ + q0w + lg * 4 + t) * D_ + h * DK_ + d * 16 + lr;
      O[idx] = f2bf(oacc[d][t] / lrow[t]);
    }
  }
}

// ---------------------------------------------------------------------------
extern "C" void kernel_launch(void* const* d_in, const int* in_sizes, int n_in,
                              void* d_out, int out_size, void* d_ws,
                              size_t ws_size, hipStream_t stream) {
  (void)in_sizes; (void)n_in; (void)out_size; (void)ws_size;
  const float* x = (const float*)d_in[0];
  const float* wq = (const float*)d_in[1];
  const float* wk = (const float*)d_in[2];
  const float* wv = (const float*)d_in[3];
  const float* wo = (const float*)d_in[4];
  const float* w1 = (const float*)d_in[5];
  const float* w2 = (const float*)d_in[6];
  const float* w3 = (const float*)d_in[7];
  const float* g1 = (const float*)d_in[8];
  const float* g2 = (const float*)d_in[9];
  const int* tp = (const int*)d_in[10];
  float* out = (float*)d_out;

  char* ws = (char*)d_ws;
  const size_t MB = 1024u * 1024u;
  // layout (128 MB total, lifetime-reused):
  u16* wqb = (u16*)(ws + 0 * MB);
  u16* wkb = (u16*)(ws + 2 * MB);
  u16* wvb = (u16*)(ws + 4 * MB);
  u16* wob = (u16*)(ws + 6 * MB);
  u16* w1b = (u16*)(ws + 8 * MB);
  u16* w2b = (u16*)(ws + 16 * MB);
  u16* w3b = (u16*)(ws + 24 * MB);
  u16* hb  = (u16*)(ws + 32 * MB);  // rmsnorm1 out; later attn-out
  float* yb = (float*)(ws + 40 * MB);  // 16MB f32
  u16* h2b = (u16*)(ws + 56 * MB);
  u16* Qb  = (u16*)(ws + 64 * MB);
  u16* Kb  = (u16*)(ws + 72 * MB);
  u16* Vb  = (u16*)(ws + 80 * MB);
  u16* Vtb = (u16*)(ws + 88 * MB);
  u16* ab  = (u16*)(ws + 64 * MB);  // 32MB, reuses Q/K/V/Vt after attention
  u16* ffb = (u16*)(ws + 96 * MB);  // 32MB
  u16* aob = hb;                    // attention output (reuses h)

  // weight conversion
  f2b_k<<<1024, 256, 0, stream>>>(wq, wqb, 262144);
  f2b_k<<<1024, 256, 0, stream>>>(wk, wkb, 262144);
  f2b_k<<<1024, 256, 0, stream>>>(wv, wvb, 262144);
  f2b_k<<<1024, 256, 0, stream>>>(wo, wob, 262144);
  f2b_k<<<4096, 256, 0, stream>>>(w1, w1b, 1048576);
  f2b_k<<<4096, 256, 0, stream>>>(w2, w2b, 1048576);
  f2b_k<<<4096, 256, 0, stream>>>(w3, w3b, 1048576);

  rmsnorm_k<<<4096, 256, 0, stream>>>(x, g1, hb);

  const dim3 gN1(8, 32), gN4(32, 32);  // (N/128, M/128)
  gemm_bt<0><<<gN1, 256, 0, stream>>>(hb, wqb, Qb, nullptr, 1024, 1024);
  gemm_bt<0><<<gN1, 256, 0, stream>>>(hb, wkb, Kb, nullptr, 1024, 1024);
  gemm_bt<0><<<gN1, 256, 0, stream>>>(hb, wvb, Vb, nullptr, 1024, 1024);

  rope_k<<<8192, 256, 0, stream>>>((unsigned int*)Qb, tp);
  rope_k<<<8192, 256, 0, stream>>>((unsigned int*)Kb, tp);
  transpose_v<<<dim3(64, 32), 256, 0, stream>>>(Vb, Vtb);

  attn_fwd<<<dim3(32, 32), 256, 0, stream>>>(Qb, Kb, Vtb, aob);

  gemm_bt<1><<<gN1, 256, 0, stream>>>(aob, wob, yb, x, 1024, 1024);  // y = x + attn@wo^T
  rmsnorm_k<<<4096, 256, 0, stream>>>(yb, g2, h2b);

  gemm_bt<0><<<gN4, 256, 0, stream>>>(h2b, w1b, ab, nullptr, 4096, 1024);       // a
  gemm_bt<2><<<gN4, 256, 0, stream>>>(h2b, w3b, ffb, ab, 4096, 1024);           // silu(a)*gate
  gemm_bt<1><<<gN1, 256, 0, stream>>>(ffb, w2b, out, yb, 1024, 4096);           // y + ff
}